// Round 1
// baseline (495.084 us; speedup 1.0000x reference)
//
#include <hip/hip_runtime.h>

typedef float v2f __attribute__((ext_vector_type(2)));
typedef float v4f __attribute__((ext_vector_type(4)));

#define B_ 64
#define N_ 4096
#define C_ 128
#define W_ 64
#define WIN_ 4033
#define CG 16       // channels per block
#define NCHUNK 256  // n per staged chunk
#define KPAD 4176   // padded w row: kk = k + 64, k in [-64, 4112)
#define WSTRIDE 338 // LDS w row stride in float2 (336 used, even for b128 alignment)

// Build interleaved, zero-padded weight table w2pad[c][kk] = (wr[c][k], wi[c][k]), k = kk-64
__global__ void prep_w(const float* __restrict__ wr, const float* __restrict__ wi,
                       v2f* __restrict__ w2pad) {
  int idx = blockIdx.x * 256 + threadIdx.x;  // exact: C_*KPAD = 2088*256
  int c = idx / KPAD;
  int kk = idx - c * KPAD;
  int k = kk - 64;
  v2f v = {0.f, 0.f};
  if (k >= 0 && k < WIN_) {
    v.x = wr[c * WIN_ + k];
    v.y = wi[c * WIN_ + k];
  }
  w2pad[idx] = v;
}

// Main: depthwise sliding correlation (both components packed) + nonlinearity + out-filter.
// Grid: 64 b * 8 cgroups = 512 blocks, 256 threads.
// Thread roles: cl = channel-in-group (16), t0g = t-block (4 x 16 t), np = n-partition (4 x 64 n/chunk).
__global__ __launch_bounds__(256, 2) void conv_main(
    const v2f* __restrict__ x2,     // [B][N][C] float2 (r,i)
    const v2f* __restrict__ w2pad,  // [C][KPAD]
    const float* __restrict__ Anl,  // [C][2][2]
    const float* __restrict__ Wcm,  // [2][2]
    const float* __restrict__ wor,  // [C][W]
    const float* __restrict__ woi,  // [C][W]
    float* __restrict__ pre) {      // [B][C][2] pre-BN
  __shared__ __attribute__((aligned(16))) v2f wsh[CG * WSTRIDE];  // 43.3 KB

  int tid = threadIdx.x;
  int bb = blockIdx.x >> 3;  // XCD-friendly: cg = bid & 7 -> each XCD sees one w-slice
  int cg = blockIdx.x & 7;
  int cbase = cg * CG;
  int cl = (tid >> 2) & 15;
  int t0g = tid & 3;
  int np = tid >> 6;
  int t0 = t0g << 4;
  int nbase = np << 6;

  v2f zero = {0.f, 0.f};
  v2f acc[16];
#pragma unroll
  for (int i = 0; i < 16; i++) acc[i] = zero;

  const v2f* xg = x2 + (size_t)bb * N_ * C_ + cbase + cl;
  const v2f* wrow = wsh + cl * WSTRIDE;

  for (int n0 = 0; n0 < N_; n0 += NCHUNK) {
    // ---- stage w chunk [n0, n0+336) for 16 channels (float4 copies) ----
    {
      const v4f* wsrc = (const v4f*)(w2pad + (size_t)cbase * KPAD + n0);
      v4f* wdst = (v4f*)wsh;
      for (int i = tid; i < CG * 168; i += 256) {
        int c = i / 168;
        int u = i - c * 168;
        wdst[c * 169 + u] = wsrc[(size_t)c * (KPAD / 2) + u];
      }
    }
    __syncthreads();

    // ---- compute: thread covers n in [n0+nbase, n0+nbase+64), t in [t0, t0+16) ----
    v2f wA[16], wB[16], xA[16], xB[16];
#pragma unroll
    for (int m = 0; m < 16; m++) wA[m] = wrow[nbase + 48 - t0 + m];  // window before nb=nbase
#pragma unroll
    for (int j = 0; j < 16; j++) xA[j] = xg[(size_t)(n0 + nbase + j) * C_];

    auto pref = [&](int nb, v2f* xv) {
#pragma unroll
      for (int j = 0; j < 16; j++) xv[j] = xg[(size_t)(n0 + nb + j) * C_];
    };
    // invariant: wold[m] = w2loc[nb+64-t0-16+m]; loads wnew[j] = w2loc[nb+64-t0+j]
    auto do16 = [&](int nb, const v2f* xv, const v2f* wold, v2f* wnew) {
#pragma unroll
      for (int j = 0; j < 16; j++) wnew[j] = wrow[nb + 64 - t0 + j];
#pragma unroll
      for (int j = 0; j < 16; j++) {
#pragma unroll
        for (int i = 0; i < 16; i++) {
          int e = j - i;  // need w2loc[nb+64-t0+(j-i)]
          v2f wv = (e < 0) ? wold[16 + e] : wnew[e];
          acc[i] = __builtin_elementwise_fma(xv[j], wv, acc[i]);
        }
      }
    };

    pref(nbase + 16, xB);
    do16(nbase + 0, xA, wA, wB);
    pref(nbase + 32, xA);
    do16(nbase + 16, xB, wB, wA);
    pref(nbase + 48, xB);
    do16(nbase + 32, xA, wA, wB);
    do16(nbase + 48, xB, wB, wA);
    __syncthreads();
  }

  // ---- reduce n-partials across np, then epilogue ----
  v2f* fpart = wsh;  // reuse: [np][cl][t] = 4*16*64 float2 = 32 KB
#pragma unroll
  for (int i = 0; i < 16; i++) fpart[((np * CG + cl) << 6) + t0 + i] = acc[i];
  __syncthreads();

  int cl2 = tid & 15;
  int tq = tid >> 4;  // 0..15
  int c = cbase + cl2;
  float a00 = Anl[c * 4 + 0], a01 = Anl[c * 4 + 1];
  float a10 = Anl[c * 4 + 2], a11 = Anl[c * 4 + 3];
  float wc00 = Wcm[0], wc01 = Wcm[1], wc10 = Wcm[2], wc11 = Wcm[3];
  float or_ = 0.f, oi_ = 0.f;
#pragma unroll
  for (int q = 0; q < 4; q++) {
    int t = tq + (q << 4);
    v2f f = fpart[(0 * CG + cl2) * 64 + t] + fpart[(1 * CG + cl2) * 64 + t] +
            fpart[(2 * CG + cl2) * 64 + t] + fpart[(3 * CG + cl2) * 64 + t];
    float ur = a00 * f.x + a01 * f.y;
    float ui = a10 * f.x + a11 * f.y;
    float amp = ur * ur + ui * ui;
    ur *= amp;
    ui *= amp;
    float vr = wc00 * ur + wc01 * ui;
    float vi = wc10 * ur + wc11 * ui;
    or_ += vr * wor[c * 64 + t];
    oi_ += vi * woi[c * 64 + t];
  }
  // combine tq within wave (lanes +16, +32 hold tq+1, tq+2/3 for same cl2)
  or_ += __shfl_down(or_, 16, 64);
  oi_ += __shfl_down(oi_, 16, 64);
  or_ += __shfl_down(or_, 32, 64);
  oi_ += __shfl_down(oi_, 32, 64);
  __syncthreads();  // done reading fpart before overwriting wsh below
  v2f* opart = wsh;  // [wave][cl2]
  if ((tid & 63) < 16) {
    v2f t = {or_, oi_};
    opart[(tid >> 6) * 16 + cl2] = t;
  }
  __syncthreads();
  if (tid < 16) {
    v2f r = opart[cl2] + opart[16 + cl2] + opart[32 + cl2] + opart[48 + cl2];
    pre[((size_t)bb * C_ + cbase + cl2) * 2 + 0] = r.x;
    pre[((size_t)bb * C_ + cbase + cl2) * 2 + 1] = r.y;
  }
}

// Train-mode BatchNorm1d over (B, comp) per channel. 128 blocks (c) x 128 threads.
__global__ void bn_kernel(const float* __restrict__ pre, const float* __restrict__ gamma,
                          const float* __restrict__ beta, float* __restrict__ out) {
  int c = blockIdx.x, tid = threadIdx.x;
  int b = tid >> 1, comp = tid & 1;
  float v = pre[((size_t)b * C_ + c) * 2 + comp];
  float s = v, s2 = v * v;
#pragma unroll
  for (int d = 32; d > 0; d >>= 1) {
    s += __shfl_down(s, d, 64);
    s2 += __shfl_down(s2, d, 64);
  }
  __shared__ float red[4];
  if ((tid & 63) == 0) {
    red[(tid >> 6) * 2 + 0] = s;
    red[(tid >> 6) * 2 + 1] = s2;
  }
  __syncthreads();
  float sum = red[0] + red[2], sumsq = red[1] + red[3];
  float mean = sum * 0.0078125f;
  float var = sumsq * 0.0078125f - mean * mean;
  float inv = rsqrtf(var + 1e-5f);
  out[((size_t)b * C_ + c) * 2 + comp] = (v - mean) * inv * gamma[c] + beta[c];
}

extern "C" void kernel_launch(void* const* d_in, const int* in_sizes, int n_in,
                              void* d_out, int out_size, void* d_ws, size_t ws_size,
                              hipStream_t stream) {
  (void)in_sizes; (void)n_in; (void)out_size; (void)ws_size;
  const float* x   = (const float*)d_in[0];
  const float* wir = (const float*)d_in[1];
  const float* wii = (const float*)d_in[2];
  const float* Anl = (const float*)d_in[3];
  const float* Wcm = (const float*)d_in[4];
  const float* wrr = (const float*)d_in[5];
  const float* wri = (const float*)d_in[6];
  const float* gam = (const float*)d_in[7];
  const float* bet = (const float*)d_in[8];

  v2f* w2pad = (v2f*)d_ws;                                        // 4.28 MB
  float* pre = (float*)((char*)d_ws + (size_t)C_ * KPAD * sizeof(v2f));  // 64 KB

  prep_w<<<(C_ * KPAD) / 256, 256, 0, stream>>>(wir, wii, w2pad);
  conv_main<<<B_ * (C_ / CG), 256, 0, stream>>>((const v2f*)x, w2pad, Anl, Wcm,
                                                wrr, wri, pre);
  bn_kernel<<<C_, 128, 0, stream>>>(pre, gam, bet, (float*)d_out);
}